// Round 3
// baseline (1588.187 us; speedup 1.0000x reference)
//
#include <hip/hip_runtime.h>
#include <math.h>

namespace {
constexpr int NPTS = 1 << 21;
constexpr int NLVL = 16;
constexpr unsigned TMASK = 0x7FFFFu;  // all hashed levels have size T = 2^19
constexpr unsigned PI1 = 2654435761u;
constexpr unsigned PI2 = 805459861u;
constexpr int BLK = 256;
constexpr int NCHUNK = NPTS / BLK;  // 8192 chunks of 256 points
constexpr int NGRID = 7;            // levels 0..6 are grid-indexed
constexpr int NCU = 256;

typedef float f2 __attribute__((ext_vector_type(2)));
typedef float f4 __attribute__((ext_vector_type(4)));

struct Params {
  float resf[NLVL];
  int off[NLVL];        // entry offsets into emb
  int cellOffB[NGRID];  // byte offsets of repacked cell tables in ws
};
}  // namespace

// ---- prologue: repack grid-level tables cell-major (8 corners = 64 B) ------
__global__ __launch_bounds__(256) void repack_kernel(
    const f2* __restrict__ emb, char* __restrict__ ws, Params p) {
  int lvl = (int)blockIdx.y;
  // static-index select chain (rule #20: no runtime index into kernarg struct)
  float rf = p.resf[0];
  int off = p.off[0], cob = p.cellOffB[0];
  if (lvl == 1) { rf = p.resf[1]; off = p.off[1]; cob = p.cellOffB[1]; }
  if (lvl == 2) { rf = p.resf[2]; off = p.off[2]; cob = p.cellOffB[2]; }
  if (lvl == 3) { rf = p.resf[3]; off = p.off[3]; cob = p.cellOffB[3]; }
  if (lvl == 4) { rf = p.resf[4]; off = p.off[4]; cob = p.cellOffB[4]; }
  if (lvl == 5) { rf = p.resf[5]; off = p.off[5]; cob = p.cellOffB[5]; }
  if (lvl == 6) { rf = p.resf[6]; off = p.off[6]; cob = p.cellOffB[6]; }
  int res = (int)rf;
  int t = (int)blockIdx.x * 256 + (int)threadIdx.x;
  if (t >= res * res * res) return;
  int x = t % res;
  int q = t / res;
  int y = q % res;
  int z = q / res;
  int s = res + 1;
  int s2 = s * s;
  const f2* base = emb + off + (x + y * s + z * s2);
  f2 e0 = base[0], e1 = base[1];
  f2 e2 = base[s], e3 = base[s + 1];
  f2 e4 = base[s2], e5 = base[s2 + 1];
  f2 e6 = base[s2 + s], e7 = base[s2 + s + 1];
  f4* dst = (f4*)(ws + (size_t)cob + (size_t)t * 64);
  f4 d0 = {e0.x, e0.y, e1.x, e1.y};  // corner order j = dx + 2*dy + 4*dz
  f4 d1 = {e2.x, e2.y, e3.x, e3.y};
  f4 d2 = {e4.x, e4.y, e5.x, e5.y};
  f4 d3 = {e6.x, e6.y, e7.x, e7.y};
  dst[0] = d0; dst[1] = d1; dst[2] = d2; dst[3] = d3;
}

// ---- per-level helpers (LVL is a template param -> all kernarg indices
// static, all hashed/grid decisions compile-time) ---------------------------

// Grid level via repacked cell table: one 64-B line per (point, level).
template <int LVL>
__device__ __forceinline__ void lvl_grid(const Params& p,
                                         const char* __restrict__ ws, float cx,
                                         float cy, float cz, float& a0,
                                         float& a1) {
  float rf = p.resf[LVL];
  int res = (int)rf;
  float sx = cx * rf, sy = cy * rf, sz = cz * rf;
  float bx = floorf(sx), by = floorf(sy), bz = floorf(sz);
  float fx = sx - bx, fy = sy - by, fz = sz - bz;
  int ix = (int)bx, iy = (int)by, iz = (int)bz;  // coords in [0,1) -> no clip
  int cell = (iz * res + iy) * res + ix;
  const f4* src = (const f4*)(ws + (size_t)p.cellOffB[LVL] + (size_t)cell * 64);
  f4 l0 = src[0], l1 = src[1], l2 = src[2], l3 = src[3];
  float wx0 = 1.f - fx, wx1 = fx;
  float wy0 = 1.f - fy, wy1 = fy;
  float wz0 = 1.f - fz, wz1 = fz;
  float w00 = wy0 * wz0, w10 = wy1 * wz0, w01 = wy0 * wz1, w11 = wy1 * wz1;
  a0 = fmaf(wx0 * w00, l0.x, a0); a1 = fmaf(wx0 * w00, l0.y, a1);
  a0 = fmaf(wx1 * w00, l0.z, a0); a1 = fmaf(wx1 * w00, l0.w, a1);
  a0 = fmaf(wx0 * w10, l1.x, a0); a1 = fmaf(wx0 * w10, l1.y, a1);
  a0 = fmaf(wx1 * w10, l1.z, a0); a1 = fmaf(wx1 * w10, l1.w, a1);
  a0 = fmaf(wx0 * w01, l2.x, a0); a1 = fmaf(wx0 * w01, l2.y, a1);
  a0 = fmaf(wx1 * w01, l2.z, a0); a1 = fmaf(wx1 * w01, l2.w, a1);
  a0 = fmaf(wx0 * w11, l3.x, a0); a1 = fmaf(wx0 * w11, l3.y, a1);
  a0 = fmaf(wx1 * w11, l3.z, a0); a1 = fmaf(wx1 * w11, l3.w, a1);
}

// Grid level direct (fallback when ws too small): 8 scattered f2 loads.
template <int LVL>
__device__ __forceinline__ void lvl_gridd(const Params& p,
                                          const f2* __restrict__ emb, float cx,
                                          float cy, float cz, float& a0,
                                          float& a1) {
  float rf = p.resf[LVL];
  int res = (int)rf;
  int s = res + 1, s2 = s * (res + 1);
  const f2* tab = emb + p.off[LVL];
  float sx = cx * rf, sy = cy * rf, sz = cz * rf;
  float bx = floorf(sx), by = floorf(sy), bz = floorf(sz);
  float fx = sx - bx, fy = sy - by, fz = sz - bz;
  int ix = (int)bx, iy = (int)by, iz = (int)bz;
  int bse = ix + iy * s + iz * s2;
  f2 e0 = tab[bse], e1 = tab[bse + 1];
  f2 e2 = tab[bse + s], e3 = tab[bse + s + 1];
  f2 e4 = tab[bse + s2], e5 = tab[bse + s2 + 1];
  f2 e6 = tab[bse + s2 + s], e7 = tab[bse + s2 + s + 1];
  float wx0 = 1.f - fx, wx1 = fx;
  float wy0 = 1.f - fy, wy1 = fy;
  float wz0 = 1.f - fz, wz1 = fz;
  float w00 = wy0 * wz0, w10 = wy1 * wz0, w01 = wy0 * wz1, w11 = wy1 * wz1;
  a0 = fmaf(wx0 * w00, e0.x, a0); a1 = fmaf(wx0 * w00, e0.y, a1);
  a0 = fmaf(wx1 * w00, e1.x, a0); a1 = fmaf(wx1 * w00, e1.y, a1);
  a0 = fmaf(wx0 * w10, e2.x, a0); a1 = fmaf(wx0 * w10, e2.y, a1);
  a0 = fmaf(wx1 * w10, e3.x, a0); a1 = fmaf(wx1 * w10, e3.y, a1);
  a0 = fmaf(wx0 * w01, e4.x, a0); a1 = fmaf(wx0 * w01, e4.y, a1);
  a0 = fmaf(wx1 * w01, e5.x, a0); a1 = fmaf(wx1 * w01, e5.y, a1);
  a0 = fmaf(wx0 * w11, e6.x, a0); a1 = fmaf(wx0 * w11, e6.y, a1);
  a0 = fmaf(wx1 * w11, e7.x, a0); a1 = fmaf(wx1 * w11, e7.y, a1);
}

__device__ __forceinline__ void hpair(const f2* __restrict__ tab, unsigned idx,
                                      float wA, float wB, float& a0,
                                      float& a1) {
  // aligned 16-B load covering {idx & ~1, idx | 1}; off even => 16-B aligned
  const f4 v = *(const f4*)(tab + (idx & ~1u));
  bool od = (idx & 1u) != 0u;
  float eAx = od ? v.z : v.x, eAy = od ? v.w : v.y;
  float eBx = od ? v.x : v.z, eBy = od ? v.y : v.w;
  a0 = fmaf(wA, eAx, a0); a1 = fmaf(wA, eAy, a1);
  a0 = fmaf(wB, eBx, a0); a1 = fmaf(wB, eBy, a1);
}

__device__ __forceinline__ void hone(const f2* __restrict__ tab, unsigned idx,
                                     float w, float& a0, float& a1) {
  f2 e = tab[idx];
  a0 = fmaf(w, e.x, a0); a1 = fmaf(w, e.y, a1);
}

template <int LVL>
__device__ __forceinline__ void lvl_hash(const Params& p,
                                         const f2* __restrict__ emb, float cx,
                                         float cy, float cz, float& a0,
                                         float& a1) {
  float rf = p.resf[LVL];
  const f2* tab = emb + p.off[LVL];
  float sx = cx * rf, sy = cy * rf, sz = cz * rf;
  float bx = floorf(sx), by = floorf(sy), bz = floorf(sz);
  float fx = sx - bx, fy = sy - by, fz = sz - bz;
  unsigned ix = (unsigned)(int)bx, iy = (unsigned)(int)by, iz = (unsigned)(int)bz;
  unsigned ty0 = iy * PI1, ty1 = ty0 + PI1;  // wraparound mul matches numpy
  unsigned tz0 = iz * PI2, tz1 = tz0 + PI2;
  unsigned e00 = ty0 ^ tz0, e10 = ty1 ^ tz0, e01 = ty0 ^ tz1, e11 = ty1 ^ tz1;
  float wx0 = 1.f - fx, wx1 = fx;
  float wy0 = 1.f - fy, wy1 = fy;
  float wz0 = 1.f - fz, wz1 = fz;
  float w00 = wy0 * wz0, w10 = wy1 * wz0, w01 = wy0 * wz1, w11 = wy1 * wz1;
  if ((ix & 1u) == 0u) {
    // ix even -> x-pair indices differ only in bit 0 for ALL 4 yz combos:
    // each pair is one aligned 16-B chunk -> 4 loads instead of 8.
    hpair(tab, (ix ^ e00) & TMASK, wx0 * w00, wx1 * w00, a0, a1);
    hpair(tab, (ix ^ e10) & TMASK, wx0 * w10, wx1 * w10, a0, a1);
    hpair(tab, (ix ^ e01) & TMASK, wx0 * w01, wx1 * w01, a0, a1);
    hpair(tab, (ix ^ e11) & TMASK, wx0 * w11, wx1 * w11, a0, a1);
  } else {
    unsigned jx = ix + 1u;
    hone(tab, (ix ^ e00) & TMASK, wx0 * w00, a0, a1);
    hone(tab, (jx ^ e00) & TMASK, wx1 * w00, a0, a1);
    hone(tab, (ix ^ e10) & TMASK, wx0 * w10, a0, a1);
    hone(tab, (jx ^ e10) & TMASK, wx1 * w10, a0, a1);
    hone(tab, (ix ^ e01) & TMASK, wx0 * w01, a0, a1);
    hone(tab, (jx ^ e01) & TMASK, wx1 * w01, a0, a1);
    hone(tab, (ix ^ e11) & TMASK, wx0 * w11, a0, a1);
    hone(tab, (jx ^ e11) & TMASK, wx1 * w11, a0, a1);
  }
}

// ---- main kernel: persistent blocks, chunk-outer / level-inner sweep.
// All resident blocks process the same level at ~the same time (table stays
// L2-resident); each thread accumulates 8 levels in regs and writes full
// 64-B output lines (2 per point) -> no partial-line RMW write traffic.
template <bool USE_WS>
__global__ void henc_main(const float* __restrict__ coords,
                          const f2* __restrict__ emb, float* __restrict__ out,
                          const char* __restrict__ ws, Params p) {
  int G = (int)gridDim.x;
  int bid = (int)blockIdx.x;
  int c0 = (int)(((long long)bid * NCHUNK) / G);
  int c1 = (int)(((long long)(bid + 1) * NCHUNK) / G);
  for (int ch = c0; ch < c1; ++ch) {
    int n = ch * BLK + (int)threadIdx.x;
    float cx = __builtin_nontemporal_load(&coords[3 * n + 0]);
    float cy = __builtin_nontemporal_load(&coords[3 * n + 1]);
    float cz = __builtin_nontemporal_load(&coords[3 * n + 2]);
    f4* o = (f4*)out + (size_t)n * 8;

    {  // group A: levels 0..7 -> first 64-B output line
      float a0 = 0, b0 = 0, a1 = 0, b1 = 0, a2 = 0, b2 = 0, a3 = 0, b3 = 0;
      float a4 = 0, b4 = 0, a5 = 0, b5 = 0, a6 = 0, b6 = 0, a7 = 0, b7 = 0;
      if (USE_WS) {
        lvl_grid<0>(p, ws, cx, cy, cz, a0, b0);
        lvl_grid<1>(p, ws, cx, cy, cz, a1, b1);
        lvl_grid<2>(p, ws, cx, cy, cz, a2, b2);
        lvl_grid<3>(p, ws, cx, cy, cz, a3, b3);
        lvl_grid<4>(p, ws, cx, cy, cz, a4, b4);
        lvl_grid<5>(p, ws, cx, cy, cz, a5, b5);
        lvl_grid<6>(p, ws, cx, cy, cz, a6, b6);
      } else {
        lvl_gridd<0>(p, emb, cx, cy, cz, a0, b0);
        lvl_gridd<1>(p, emb, cx, cy, cz, a1, b1);
        lvl_gridd<2>(p, emb, cx, cy, cz, a2, b2);
        lvl_gridd<3>(p, emb, cx, cy, cz, a3, b3);
        lvl_gridd<4>(p, emb, cx, cy, cz, a4, b4);
        lvl_gridd<5>(p, emb, cx, cy, cz, a5, b5);
        lvl_gridd<6>(p, emb, cx, cy, cz, a6, b6);
      }
      lvl_hash<7>(p, emb, cx, cy, cz, a7, b7);
      f4 v0 = {a0, b0, a1, b1};
      f4 v1 = {a2, b2, a3, b3};
      f4 v2 = {a4, b4, a5, b5};
      f4 v3 = {a6, b6, a7, b7};
      o[0] = v0; o[1] = v1; o[2] = v2; o[3] = v3;
    }
    {  // group B: levels 8..15 -> second 64-B output line
      float a0 = 0, b0 = 0, a1 = 0, b1 = 0, a2 = 0, b2 = 0, a3 = 0, b3 = 0;
      float a4 = 0, b4 = 0, a5 = 0, b5 = 0, a6 = 0, b6 = 0, a7 = 0, b7 = 0;
      lvl_hash<8>(p, emb, cx, cy, cz, a0, b0);
      lvl_hash<9>(p, emb, cx, cy, cz, a1, b1);
      lvl_hash<10>(p, emb, cx, cy, cz, a2, b2);
      lvl_hash<11>(p, emb, cx, cy, cz, a3, b3);
      lvl_hash<12>(p, emb, cx, cy, cz, a4, b4);
      lvl_hash<13>(p, emb, cx, cy, cz, a5, b5);
      lvl_hash<14>(p, emb, cx, cy, cz, a6, b6);
      lvl_hash<15>(p, emb, cx, cy, cz, a7, b7);
      f4 v0 = {a0, b0, a1, b1};
      f4 v1 = {a2, b2, a3, b3};
      f4 v2 = {a4, b4, a5, b5};
      f4 v3 = {a6, b6, a7, b7};
      o[4] = v0; o[5] = v1; o[6] = v2; o[7] = v3;
    }
  }
}

extern "C" void kernel_launch(void* const* d_in, const int* in_sizes, int n_in,
                              void* d_out, int out_size, void* d_ws,
                              size_t ws_size, hipStream_t stream) {
  const float* coords = (const float*)d_in[0];
  const f2* emb = (const f2*)d_in[1];
  float* out = (float*)d_out;

  // Replicate Python's level_params() bit-exactly with host libm doubles.
  Params p;
  double b = pow(32.0, 1.0 / 15.0);
  long long cum = 0, cellCum = 0;
  int res6 = 64;
  for (int i = 0; i < NLVL; ++i) {
    int r = (int)floor(16.0 * pow(b, (double)i));
    p.resf[i] = (float)r;
    p.off[i] = (int)cum;
    long long e3 = (long long)(r + 1) * (r + 1) * (r + 1);
    cum += e3 > 524288 ? 524288 : e3;
    if (i < NGRID) {
      p.cellOffB[i] = (int)(cellCum * 64);
      cellCum += (long long)r * r * r;
      if (i == NGRID - 1) res6 = r;
    }
  }
  size_t wsNeed = (size_t)cellCum * 64;  // ~31.2 MB
  bool useWs = ws_size >= wsNeed;

  if (useWs) {
    int bx = (res6 * res6 * res6 + 255) / 256;
    repack_kernel<<<dim3(bx, NGRID), dim3(256), 0, stream>>>(emb, (char*)d_ws, p);
    int nb = 0;
    if (hipOccupancyMaxActiveBlocksPerMultiprocessor(&nb, henc_main<true>, BLK,
                                                     0) != hipSuccess ||
        nb < 1)
      nb = 4;
    int G = nb * NCU;
    if (G > NCHUNK) G = NCHUNK;
    henc_main<true><<<dim3(G), dim3(BLK), 0, stream>>>(coords, emb, out,
                                                       (const char*)d_ws, p);
  } else {
    int nb = 0;
    if (hipOccupancyMaxActiveBlocksPerMultiprocessor(&nb, henc_main<false>, BLK,
                                                     0) != hipSuccess ||
        nb < 1)
      nb = 4;
    int G = nb * NCU;
    if (G > NCHUNK) G = NCHUNK;
    henc_main<false><<<dim3(G), dim3(BLK), 0, stream>>>(coords, emb, out,
                                                        (const char*)d_ws, p);
  }
}

// Round 4
// 1229.731 us; speedup vs baseline: 1.2915x; 1.2915x over previous
//
#include <hip/hip_runtime.h>
#include <math.h>

namespace {
constexpr int NPTS = 1 << 21;
constexpr int NLVL = 16;
constexpr unsigned TMASK = 0x7FFFFu;  // all hashed levels have size T = 2^19
constexpr unsigned PI1 = 2654435761u;
constexpr unsigned PI2 = 805459861u;
constexpr int BLK = 512;
constexpr int PTS_PER_BLK = 1024;
constexpr int NBLK = NPTS / PTS_PER_BLK;  // 2048
constexpr int NGRID = 7;                  // levels 0..6 grid-indexed

typedef float f2 __attribute__((ext_vector_type(2)));
typedef float f4 __attribute__((ext_vector_type(4)));

struct Params {
  float resf[NLVL];
  int off[NLVL];        // entry offsets into emb
  int cellOffB[NGRID];  // byte offsets of repacked cell tables in ws
};

// LDS column swizzle: spreads the per-level write (fixed col across 64 lanes)
// over 8 bank-pairs -> ~4-way conflict instead of 32-way.
__device__ __forceinline__ int swz(int pt) { return (pt ^ (pt >> 3)) & 7; }
}  // namespace

// ---- prologue: repack grid-level tables cell-major (8 corners = 64 B) ------
__global__ __launch_bounds__(256) void repack_kernel(
    const f2* __restrict__ emb, char* __restrict__ ws, Params p) {
  int lvl = (int)blockIdx.y;
  // static-index select chain (rule #20)
  float rf = p.resf[0];
  int off = p.off[0], cob = p.cellOffB[0];
  if (lvl == 1) { rf = p.resf[1]; off = p.off[1]; cob = p.cellOffB[1]; }
  if (lvl == 2) { rf = p.resf[2]; off = p.off[2]; cob = p.cellOffB[2]; }
  if (lvl == 3) { rf = p.resf[3]; off = p.off[3]; cob = p.cellOffB[3]; }
  if (lvl == 4) { rf = p.resf[4]; off = p.off[4]; cob = p.cellOffB[4]; }
  if (lvl == 5) { rf = p.resf[5]; off = p.off[5]; cob = p.cellOffB[5]; }
  if (lvl == 6) { rf = p.resf[6]; off = p.off[6]; cob = p.cellOffB[6]; }
  int res = (int)rf;
  int t = (int)blockIdx.x * 256 + (int)threadIdx.x;
  if (t >= res * res * res) return;
  int x = t % res;
  int q = t / res;
  int y = q % res;
  int z = q / res;
  int s = res + 1;
  int s2 = s * s;
  const f2* base = emb + off + (x + y * s + z * s2);
  f2 e0 = base[0], e1 = base[1];
  f2 e2 = base[s], e3 = base[s + 1];
  f2 e4 = base[s2], e5 = base[s2 + 1];
  f2 e6 = base[s2 + s], e7 = base[s2 + s + 1];
  f4* dst = (f4*)(ws + (size_t)cob + (size_t)t * 64);
  f4 d0 = {e0.x, e0.y, e1.x, e1.y};  // corner order j = dx + 2*dy + 4*dz
  f4 d1 = {e2.x, e2.y, e3.x, e3.y};
  f4 d2 = {e4.x, e4.y, e5.x, e5.y};
  f4 d3 = {e6.x, e6.y, e7.x, e7.y};
  dst[0] = d0; dst[1] = d1; dst[2] = d2; dst[3] = d3;
}

// ---- per-level compute helpers (LVL compile-time -> static kernarg idx) ----

template <int LVL>
__device__ __forceinline__ f2 grid_ws(const Params& p,
                                      const char* __restrict__ ws, float cx,
                                      float cy, float cz) {
  float rf = p.resf[LVL];
  int res = (int)rf;
  float sx = cx * rf, sy = cy * rf, sz = cz * rf;
  float bx = floorf(sx), by = floorf(sy), bz = floorf(sz);
  float fx = sx - bx, fy = sy - by, fz = sz - bz;
  int ix = (int)bx, iy = (int)by, iz = (int)bz;  // coords in [0,1): no clip
  int cell = (iz * res + iy) * res + ix;
  const f4* src = (const f4*)(ws + (size_t)p.cellOffB[LVL] + (size_t)cell * 64);
  f4 l0 = src[0], l1 = src[1], l2 = src[2], l3 = src[3];
  float wx0 = 1.f - fx, wx1 = fx;
  float wy0 = 1.f - fy, wy1 = fy;
  float wz0 = 1.f - fz, wz1 = fz;
  float w00 = wy0 * wz0, w10 = wy1 * wz0, w01 = wy0 * wz1, w11 = wy1 * wz1;
  float a0 = 0.f, a1 = 0.f;
  a0 = fmaf(wx0 * w00, l0.x, a0); a1 = fmaf(wx0 * w00, l0.y, a1);
  a0 = fmaf(wx1 * w00, l0.z, a0); a1 = fmaf(wx1 * w00, l0.w, a1);
  a0 = fmaf(wx0 * w10, l1.x, a0); a1 = fmaf(wx0 * w10, l1.y, a1);
  a0 = fmaf(wx1 * w10, l1.z, a0); a1 = fmaf(wx1 * w10, l1.w, a1);
  a0 = fmaf(wx0 * w01, l2.x, a0); a1 = fmaf(wx0 * w01, l2.y, a1);
  a0 = fmaf(wx1 * w01, l2.z, a0); a1 = fmaf(wx1 * w01, l2.w, a1);
  a0 = fmaf(wx0 * w11, l3.x, a0); a1 = fmaf(wx0 * w11, l3.y, a1);
  a0 = fmaf(wx1 * w11, l3.z, a0); a1 = fmaf(wx1 * w11, l3.w, a1);
  f2 r; r.x = a0; r.y = a1;
  return r;
}

template <int LVL>
__device__ __forceinline__ f2 grid_direct(const Params& p,
                                          const f2* __restrict__ emb, float cx,
                                          float cy, float cz) {
  float rf = p.resf[LVL];
  int res = (int)rf;
  int s = res + 1, s2 = s * s;
  const f2* tab = emb + p.off[LVL];
  float sx = cx * rf, sy = cy * rf, sz = cz * rf;
  float bx = floorf(sx), by = floorf(sy), bz = floorf(sz);
  float fx = sx - bx, fy = sy - by, fz = sz - bz;
  int ix = (int)bx, iy = (int)by, iz = (int)bz;
  int bse = ix + iy * s + iz * s2;
  f2 e0 = tab[bse], e1 = tab[bse + 1];
  f2 e2 = tab[bse + s], e3 = tab[bse + s + 1];
  f2 e4 = tab[bse + s2], e5 = tab[bse + s2 + 1];
  f2 e6 = tab[bse + s2 + s], e7 = tab[bse + s2 + s + 1];
  float wx0 = 1.f - fx, wx1 = fx;
  float wy0 = 1.f - fy, wy1 = fy;
  float wz0 = 1.f - fz, wz1 = fz;
  float w00 = wy0 * wz0, w10 = wy1 * wz0, w01 = wy0 * wz1, w11 = wy1 * wz1;
  float a0 = 0.f, a1 = 0.f;
  a0 = fmaf(wx0 * w00, e0.x, a0); a1 = fmaf(wx0 * w00, e0.y, a1);
  a0 = fmaf(wx1 * w00, e1.x, a0); a1 = fmaf(wx1 * w00, e1.y, a1);
  a0 = fmaf(wx0 * w10, e2.x, a0); a1 = fmaf(wx0 * w10, e2.y, a1);
  a0 = fmaf(wx1 * w10, e3.x, a0); a1 = fmaf(wx1 * w10, e3.y, a1);
  a0 = fmaf(wx0 * w01, e4.x, a0); a1 = fmaf(wx0 * w01, e4.y, a1);
  a0 = fmaf(wx1 * w01, e5.x, a0); a1 = fmaf(wx1 * w01, e5.y, a1);
  a0 = fmaf(wx0 * w11, e6.x, a0); a1 = fmaf(wx0 * w11, e6.y, a1);
  a0 = fmaf(wx1 * w11, e7.x, a0); a1 = fmaf(wx1 * w11, e7.y, a1);
  f2 r; r.x = a0; r.y = a1;
  return r;
}

__device__ __forceinline__ void hpair(const f2* __restrict__ tab, unsigned idx,
                                      float wA, float wB, float& a0,
                                      float& a1) {
  // one 16-B load covering the {even, odd} index pair (validated round 3)
  const f4 v = *(const f4*)(tab + (idx & ~1u));
  bool od = (idx & 1u) != 0u;
  float eAx = od ? v.z : v.x, eAy = od ? v.w : v.y;
  float eBx = od ? v.x : v.z, eBy = od ? v.y : v.w;
  a0 = fmaf(wA, eAx, a0); a1 = fmaf(wA, eAy, a1);
  a0 = fmaf(wB, eBx, a0); a1 = fmaf(wB, eBy, a1);
}

__device__ __forceinline__ void hone(const f2* __restrict__ tab, unsigned idx,
                                     float w, float& a0, float& a1) {
  f2 e = tab[idx];
  a0 = fmaf(w, e.x, a0); a1 = fmaf(w, e.y, a1);
}

template <int LVL>
__device__ __forceinline__ f2 hash_lvl(const Params& p,
                                       const f2* __restrict__ emb, float cx,
                                       float cy, float cz) {
  float rf = p.resf[LVL];
  const f2* tab = emb + p.off[LVL];
  float sx = cx * rf, sy = cy * rf, sz = cz * rf;
  float bx = floorf(sx), by = floorf(sy), bz = floorf(sz);
  float fx = sx - bx, fy = sy - by, fz = sz - bz;
  unsigned ix = (unsigned)(int)bx, iy = (unsigned)(int)by,
           iz = (unsigned)(int)bz;
  unsigned ty0 = iy * PI1, ty1 = ty0 + PI1;  // wraparound mul matches numpy
  unsigned tz0 = iz * PI2, tz1 = tz0 + PI2;
  unsigned e00 = ty0 ^ tz0, e10 = ty1 ^ tz0, e01 = ty0 ^ tz1, e11 = ty1 ^ tz1;
  float wx0 = 1.f - fx, wx1 = fx;
  float wy0 = 1.f - fy, wy1 = fy;
  float wz0 = 1.f - fz, wz1 = fz;
  float w00 = wy0 * wz0, w10 = wy1 * wz0, w01 = wy0 * wz1, w11 = wy1 * wz1;
  float a0 = 0.f, a1 = 0.f;
  if ((ix & 1u) == 0u) {
    // even ix: x-pair differs only in bit0 for all 4 yz combos -> 4 loads
    hpair(tab, (ix ^ e00) & TMASK, wx0 * w00, wx1 * w00, a0, a1);
    hpair(tab, (ix ^ e10) & TMASK, wx0 * w10, wx1 * w10, a0, a1);
    hpair(tab, (ix ^ e01) & TMASK, wx0 * w01, wx1 * w01, a0, a1);
    hpair(tab, (ix ^ e11) & TMASK, wx0 * w11, wx1 * w11, a0, a1);
  } else {
    unsigned jx = ix + 1u;
    hone(tab, (ix ^ e00) & TMASK, wx0 * w00, a0, a1);
    hone(tab, (jx ^ e00) & TMASK, wx1 * w00, a0, a1);
    hone(tab, (ix ^ e10) & TMASK, wx0 * w10, a0, a1);
    hone(tab, (jx ^ e10) & TMASK, wx1 * w10, a0, a1);
    hone(tab, (ix ^ e01) & TMASK, wx0 * w01, a0, a1);
    hone(tab, (jx ^ e01) & TMASK, wx1 * w01, a0, a1);
    hone(tab, (ix ^ e11) & TMASK, wx0 * w11, a0, a1);
    hone(tab, (jx ^ e11) & TMASK, wx1 * w11, a0, a1);
  }
  f2 r; r.x = a0; r.y = a1;
  return r;
}

// ---- main: level-outer sweep with LDS result accumulator -------------------

template <int LVL, bool USE_WS>
__device__ __forceinline__ void do_phase(const Params& p,
                                         const f2* __restrict__ emb,
                                         const char* __restrict__ ws,
                                         const float* cx, const float* cy,
                                         const float* cz, int tid, f2* lds) {
#pragma unroll
  for (int q = 0; q < 2; ++q) {
    int pt = tid + BLK * q;
    f2 r;
    if constexpr (LVL < NGRID) {
      if constexpr (USE_WS)
        r = grid_ws<LVL>(p, ws, cx[q], cy[q], cz[q]);
      else
        r = grid_direct<LVL>(p, emb, cx[q], cy[q], cz[q]);
    } else {
      r = hash_lvl<LVL>(p, emb, cx[q], cy[q], cz[q]);
    }
    lds[pt * 8 + ((LVL & 7) ^ swz(pt))] = r;
  }
}

// Readout half-sweep h: every f4 store instr is lane-consecutive 16 B chunks
// covering full 64-B lines (lanes 4k..4k+3 cover one point's 64-B half-row).
__device__ __forceinline__ void readout(float* __restrict__ out, const f2* lds,
                                        int n0, int h, int tid) {
#pragma unroll
  for (int j = 0; j < 8; ++j) {
    int f = tid + BLK * j;  // f4 index 0..4095
    int pt = f >> 2, k = f & 3;
    int s = swz(pt);
    f2 v0 = lds[pt * 8 + ((2 * k) ^ s)];
    f2 v1 = lds[pt * 8 + ((2 * k + 1) ^ s)];
    f4 o4; o4.x = v0.x; o4.y = v0.y; o4.z = v1.x; o4.w = v1.y;
    __builtin_nontemporal_store(
        o4, (f4*)(out + (size_t)(n0 + pt) * 32 + h * 16 + k * 4));
  }
}

template <bool USE_WS>
__global__ __launch_bounds__(BLK, 4) void henc(const float* __restrict__ coords,
                                               const f2* __restrict__ emb,
                                               float* __restrict__ out,
                                               const char* __restrict__ ws,
                                               Params p) {
  __shared__ f2 lds[PTS_PER_BLK * 8];  // 64 KB
  const int tid = (int)threadIdx.x;
  const int n0 = (int)blockIdx.x * PTS_PER_BLK;

  // coords read ONCE per point for all 16 levels (vs 16x in round 2)
  float cx[2], cy[2], cz[2];
#pragma unroll
  for (int q = 0; q < 2; ++q) {
    int n = n0 + tid + BLK * q;
    cx[q] = __builtin_nontemporal_load(&coords[3 * n + 0]);
    cy[q] = __builtin_nontemporal_load(&coords[3 * n + 1]);
    cz[q] = __builtin_nontemporal_load(&coords[3 * n + 2]);
  }

  // half A: levels 0..7 (level-outer -> one table hot at a time, soft-phased
  // across blocks by in-order dispatch + identical per-level work)
  do_phase<0, USE_WS>(p, emb, ws, cx, cy, cz, tid, lds);
  do_phase<1, USE_WS>(p, emb, ws, cx, cy, cz, tid, lds);
  do_phase<2, USE_WS>(p, emb, ws, cx, cy, cz, tid, lds);
  do_phase<3, USE_WS>(p, emb, ws, cx, cy, cz, tid, lds);
  do_phase<4, USE_WS>(p, emb, ws, cx, cy, cz, tid, lds);
  do_phase<5, USE_WS>(p, emb, ws, cx, cy, cz, tid, lds);
  do_phase<6, USE_WS>(p, emb, ws, cx, cy, cz, tid, lds);
  do_phase<7, USE_WS>(p, emb, ws, cx, cy, cz, tid, lds);
  __syncthreads();
  readout(out, lds, n0, 0, tid);
  __syncthreads();  // LDS reuse fence

  // half B: levels 8..15
  do_phase<8, USE_WS>(p, emb, ws, cx, cy, cz, tid, lds);
  do_phase<9, USE_WS>(p, emb, ws, cx, cy, cz, tid, lds);
  do_phase<10, USE_WS>(p, emb, ws, cx, cy, cz, tid, lds);
  do_phase<11, USE_WS>(p, emb, ws, cx, cy, cz, tid, lds);
  do_phase<12, USE_WS>(p, emb, ws, cx, cy, cz, tid, lds);
  do_phase<13, USE_WS>(p, emb, ws, cx, cy, cz, tid, lds);
  do_phase<14, USE_WS>(p, emb, ws, cx, cy, cz, tid, lds);
  do_phase<15, USE_WS>(p, emb, ws, cx, cy, cz, tid, lds);
  __syncthreads();
  readout(out, lds, n0, 1, tid);
}

extern "C" void kernel_launch(void* const* d_in, const int* in_sizes, int n_in,
                              void* d_out, int out_size, void* d_ws,
                              size_t ws_size, hipStream_t stream) {
  const float* coords = (const float*)d_in[0];
  const f2* emb = (const f2*)d_in[1];
  float* out = (float*)d_out;

  // Replicate Python's level_params() bit-exactly with host libm doubles.
  Params p;
  double b = pow(32.0, 1.0 / 15.0);
  long long cum = 0, cellCum = 0;
  int res6 = 64;
  for (int i = 0; i < NLVL; ++i) {
    int r = (int)floor(16.0 * pow(b, (double)i));
    p.resf[i] = (float)r;
    p.off[i] = (int)cum;
    long long e3 = (long long)(r + 1) * (r + 1) * (r + 1);
    cum += e3 > 524288 ? 524288 : e3;
    if (i < NGRID) {
      p.cellOffB[i] = (int)(cellCum * 64);
      cellCum += (long long)r * r * r;
      if (i == NGRID - 1) res6 = r;
    }
  }
  size_t wsNeed = (size_t)cellCum * 64;  // ~31 MB
  bool useWs = ws_size >= wsNeed;

  if (useWs) {
    int bx = (res6 * res6 * res6 + 255) / 256;
    repack_kernel<<<dim3(bx, NGRID), dim3(256), 0, stream>>>(emb, (char*)d_ws,
                                                             p);
    henc<true><<<dim3(NBLK), dim3(BLK), 0, stream>>>(coords, emb, out,
                                                     (const char*)d_ws, p);
  } else {
    henc<false><<<dim3(NBLK), dim3(BLK), 0, stream>>>(coords, emb, out,
                                                      (const char*)d_ws, p);
  }
}